// Round 12
// baseline (157.721 us; speedup 1.0000x reference)
//
#include <hip/hip_runtime.h>

#define F 64
#define NPART 256
#define CAP 8192   // per-partition staging capacity; mean 4883 -> huge slack

typedef unsigned short u16x8 __attribute__((ext_vector_type(8)));
typedef unsigned short u16x4 __attribute__((ext_vector_type(4)));
typedef _Float16       f16x8 __attribute__((ext_vector_type(8)));
typedef _Float16       f16x4 __attribute__((ext_vector_type(4)));
typedef float          f32x4 __attribute__((ext_vector_type(4)));

// ---- fp16 helpers ----
__device__ __forceinline__ float h2f(unsigned short u) {
    _Float16 h; __builtin_memcpy(&h, &u, 2); return (float)h;
}
__device__ __forceinline__ unsigned short f2h(float f) {
    _Float16 h = (_Float16)f; unsigned short u; __builtin_memcpy(&u, &h, 2); return u;
}

// ======================= CSR build =======================

__global__ void k_binit(int* bbase) {
    bbase[threadIdx.x * 16] = threadIdx.x * CAP;
}

// Fused: blocks [0,nBin) bin edges; blocks [nBin,..) do GEMM1 (x @ W1 -> mhA,
// fp16, UNSCALED — k_sortP's tail scales by isd once isd exists).
template<int EPT>
__global__ __launch_bounds__(256)
void k_binGemm1(const int* __restrict__ src, const int* __restrict__ dst,
                int* bbase, int2* staging,
                const float* __restrict__ x, const float* __restrict__ W1,
                unsigned short* __restrict__ mhA,
                int nE, int nN, int nBin, int nTiles)
{
    __shared__ int lcnt[NPART];
    __shared__ int lbase[NPART];
    __shared__ _Float16 Wt[64 * 72];
    const int t = threadIdx.x;

    if (blockIdx.x < nBin) {
        // ---------------- bin path ----------------
        const int i0 = blockIdx.x * 256 * EPT;
        lcnt[t] = 0;
        __syncthreads();
        int es[EPT], ed[EPT], bk[EPT];
#pragma unroll
        for (int k = 0; k < EPT; ++k) {
            const int i = i0 + k * 256 + t;
            if (i < nE) {
                es[k] = src[i];
                ed[k] = dst[i];
                bk[k] = (int)(((long long)ed[k] * NPART) / nN);
                atomicAdd(&lcnt[bk[k]], 1);
            } else bk[k] = -1;
        }
        __syncthreads();
        lbase[t] = atomicAdd(&bbase[t * 16], lcnt[t]);
        lcnt[t] = 0;
        __syncthreads();
#pragma unroll
        for (int k = 0; k < EPT; ++k) {
            if (bk[k] >= 0) {
                const int r   = atomicAdd(&lcnt[bk[k]], 1);
                const int pos = lbase[bk[k]] + r;
                if (pos < (bk[k] + 1) * CAP)
                    staging[pos] = make_int2(es[k], ed[k]);
            }
        }
    } else {
        // ---------------- GEMM1 path (f32 in, no act, fp16 out) ----------------
#pragma unroll
        for (int i = 0; i < 16; ++i) {
            const int idx = i * 256 + t;
            Wt[(idx & 63) * 72 + (idx >> 6)] = (_Float16)W1[idx];
        }
        __syncthreads();
        const int w    = t >> 6;
        const int l    = t & 63;
        const int lr   = l & 15;
        const int lg   = l >> 4;
        const int tile = (blockIdx.x - nBin) * 4 + w;
        if (tile >= nTiles) return;

        f16x8 bf[2][4];
#pragma unroll
        for (int kt = 0; kt < 2; ++kt)
#pragma unroll
            for (int ct = 0; ct < 4; ++ct)
                bf[kt][ct] = *(const f16x8*)&Wt[(ct * 16 + lr) * 72 + kt * 32 + lg * 8];

        const float* rp = x + (size_t)(tile * 16 + lr) * F;
        f16x8 af[2];
#pragma unroll
        for (int kt = 0; kt < 2; ++kt) {
            const float4 v0 = *(const float4*)(rp + kt * 32 + lg * 8);
            const float4 v1 = *(const float4*)(rp + kt * 32 + lg * 8 + 4);
            f16x8 a;
            a[0] = (_Float16)v0.x; a[1] = (_Float16)v0.y;
            a[2] = (_Float16)v0.z; a[3] = (_Float16)v0.w;
            a[4] = (_Float16)v1.x; a[5] = (_Float16)v1.y;
            a[6] = (_Float16)v1.z; a[7] = (_Float16)v1.w;
            af[kt] = a;
        }

        f32x4 acc[4] = {{0.f,0.f,0.f,0.f},{0.f,0.f,0.f,0.f},{0.f,0.f,0.f,0.f},{0.f,0.f,0.f,0.f}};
#pragma unroll
        for (int kt = 0; kt < 2; ++kt)
#pragma unroll
            for (int ct = 0; ct < 4; ++ct)
                acc[ct] = __builtin_amdgcn_mfma_f32_16x16x32_f16(af[kt], bf[kt][ct], acc[ct], 0, 0, 0);

        const int rowb = tile * 16 + lg * 4;
#pragma unroll
        for (int ct = 0; ct < 4; ++ct) {
            const int c = ct * 16 + lr;
#pragma unroll
            for (int r = 0; r < 4; ++r)
                mhA[(size_t)(rowb + r) * F + c] = f2h(acc[ct][r]);
        }
    }
}

// One block (256 threads) per partition p: LDS counting sort of staging slice,
// then scale tail: mhA[row] *= isd[row] (pre-scaling for the gather).
__global__ __launch_bounds__(256)
void k_sortP(const int2* __restrict__ staging, const int* __restrict__ bbase,
             int* __restrict__ ebs, int* __restrict__ rowptr,
             float* __restrict__ isd, unsigned short* __restrict__ mhA,
             int nN, int nE) {
    __shared__ int pc[NPART];
    __shared__ int pcv[NPART];
    __shared__ int cnt[512];
    __shared__ int cur[512];
    const int p = blockIdx.x;
    const int t = threadIdx.x;

    int cval = bbase[t * 16] - t * CAP;
    if (cval > CAP) cval = CAP;
    if (cval < 0)   cval = 0;
    pc[t]  = cval;
    pcv[t] = cval;
    __syncthreads();
#pragma unroll
    for (int off = 1; off < NPART; off <<= 1) {
        const int a = (t >= off) ? pc[t - off] : 0;
        __syncthreads();
        pc[t] += a;
        __syncthreads();
    }
    const int cg    = pcv[p];
    const int ebase = pc[p] - cg;
    // EXACT inverse of bucket(): lo = ceil(p*nN/NPART)
    const int lo    = (int)(((long long)nN * p + NPART - 1) / NPART);
    const int hi    = (int)(((long long)nN * (p + 1) + NPART - 1) / NPART);
    const int npn   = hi - lo;

    cnt[t] = 0; cnt[t + 256] = 0;
    __syncthreads();
    const int2* st = staging + (size_t)p * CAP;
    for (int j = t; j < cg; j += 256) atomicAdd(&cnt[st[j].y - lo], 1);
    __syncthreads();

    const int c0 = cnt[t], c1 = cnt[t + 256];
#pragma unroll
    for (int off = 1; off < 512; off <<= 1) {
        const int a0 = (t >= off) ? cnt[t - off] : 0;
        const int a1 = (t + 256 >= off) ? cnt[t + 256 - off] : 0;
        __syncthreads();
        cnt[t] += a0; cnt[t + 256] += a1;
        __syncthreads();
    }
    const int e0 = cnt[t] - c0, e1 = cnt[t + 256] - c1;
    cur[t] = e0; cur[t + 256] = e1;

    if (t < npn)        { rowptr[lo + t]        = ebase + e0; isd[lo + t]        = rsqrtf((float)c0 + 1.0f); }
    if (t + 256 < npn)  { rowptr[lo + t + 256]  = ebase + e1; isd[lo + t + 256]  = rsqrtf((float)c1 + 1.0f); }
    if (p == NPART - 1 && t == 0) rowptr[nN] = ebase + cg;
    __syncthreads();

    for (int j = t; j < cg; j += 256) {
        const int2 e = st[j];
        const int  r = atomicAdd(&cur[e.y - lo], 1);
        ebs[ebase + r] = e.x;
    }

    // ---- scale tail: mhA[row] *= isd[row] for rows [lo, hi) ----
    for (int r = t; r < npn; r += 256) {
        const int row = lo + r;
        const float sr = isd[row];
        u16x8* rp = (u16x8*)(mhA + (size_t)row * F);
#pragma unroll
        for (int q = 0; q < 8; ++q) {
            u16x8 v = rp[q];
            u16x8 o;
#pragma unroll
            for (int j = 0; j < 8; ++j) o[j] = f2h(h2f(v[j]) * sr);
            rp[q] = o;
        }
    }
}

// ======================= fused agg + GEMM =======================
// Block = 32 nodes, 4 waves; agg: wave w computes nodes nb+w*8+i (i=0..7).
// Packed gather: lane l = 16q + r loads u16x4 (features [4r,4r+4)) of row
// ebs[e+q] -> one VMEM instruction covers 4 rows. acc reduced across q-groups
// via shfl_xor(16,32); q==0 lanes apply *di + bias, relu -> LDS A (fp16).
// mh' is pre-scaled by isd so the edge loop has NO weight loads.
// GEMM: wave w -> 16-row tile (w>>1), col-tiles {(w&1)*2, +1}.
// Epilogue: PROJ ? z=f32(acc+bout) : mhOut = fp16(acc * isd[row]) (pre-scaled).
// nN must be a multiple of 32 (100000 = 3125*32).

template<bool PROJ>
__global__ __launch_bounds__(256)
void k_aggGemm(const unsigned short* __restrict__ mhIn,
               const float* __restrict__ isd,
               const int* __restrict__ rowptr, const int* __restrict__ ebs,
               const float* __restrict__ W, const float* __restrict__ bin,
               const float* __restrict__ bout,
               unsigned short* __restrict__ outh, float* __restrict__ outf,
               int nN)
{
    __shared__ _Float16 Wt[64 * 72];
    __shared__ _Float16 A[32 * 72];
    const int t = threadIdx.x;
#pragma unroll
    for (int i = 0; i < 16; ++i) {
        const int idx = i * 256 + t;
        Wt[(idx & 63) * 72 + (idx >> 6)] = (_Float16)W[idx];
    }

    const int w  = t >> 6;
    const int l  = t & 63;
    const int q  = l >> 4;          // row slot (0..3)
    const int r  = l & 15;          // feature quad (0..15)
    const int nb = blockIdx.x * 32;
    const float4 bb = *(const float4*)(bin + r * 4);   // bias for features 4r..4r+3

#pragma unroll
    for (int i = 0; i < 8; ++i) {
        const int n = nb + w * 8 + i;
        const int beg = __builtin_amdgcn_readfirstlane(rowptr[n]);
        const int end = __builtin_amdgcn_readfirstlane(rowptr[n + 1]);
        const float di = isd[n];
        float a0 = 0.f, a1 = 0.f, a2 = 0.f, a3 = 0.f;
        float b0 = 0.f, b1 = 0.f, b2 = 0.f, b3 = 0.f;
        if (q == 0) {   // self term (mh' = m*isd), counted exactly once
            const u16x4 sv = *(const u16x4*)(mhIn + (size_t)n * F + r * 4);
            a0 = h2f(sv[0]); a1 = h2f(sv[1]); a2 = h2f(sv[2]); a3 = h2f(sv[3]);
        }
        int e = beg;
        for (; e + 16 <= end; e += 16) {
            const int s0 = ebs[e + q];
            const int s1 = ebs[e + 4 + q];
            const int s2 = ebs[e + 8 + q];
            const int s3 = ebs[e + 12 + q];
            const u16x4 v0 = *(const u16x4*)(mhIn + (size_t)s0 * F + r * 4);
            const u16x4 v1 = *(const u16x4*)(mhIn + (size_t)s1 * F + r * 4);
            const u16x4 v2 = *(const u16x4*)(mhIn + (size_t)s2 * F + r * 4);
            const u16x4 v3 = *(const u16x4*)(mhIn + (size_t)s3 * F + r * 4);
            a0 += h2f(v0[0]); a1 += h2f(v0[1]); a2 += h2f(v0[2]); a3 += h2f(v0[3]);
            b0 += h2f(v1[0]); b1 += h2f(v1[1]); b2 += h2f(v1[2]); b3 += h2f(v1[3]);
            a0 += h2f(v2[0]); a1 += h2f(v2[1]); a2 += h2f(v2[2]); a3 += h2f(v2[3]);
            b0 += h2f(v3[0]); b1 += h2f(v3[1]); b2 += h2f(v3[2]); b3 += h2f(v3[3]);
        }
        for (; e < end; e += 4) {           // tail: clamp + mask (<=3 iters)
            const int idx = e + q;
            const int sc  = (idx < end) ? idx : end - 1;
            const int s0  = ebs[sc];
            const u16x4 v0 = *(const u16x4*)(mhIn + (size_t)s0 * F + r * 4);
            const float msk = (idx < end) ? 1.f : 0.f;
            b0 = fmaf(msk, h2f(v0[0]), b0);
            b1 = fmaf(msk, h2f(v0[1]), b1);
            b2 = fmaf(msk, h2f(v0[2]), b2);
            b3 = fmaf(msk, h2f(v0[3]), b3);
        }
        a0 += b0; a1 += b1; a2 += b2; a3 += b3;
        // reduce across the 4 q-groups (lanes ^16, ^32)
        a0 += __shfl_xor(a0, 16); a1 += __shfl_xor(a1, 16);
        a2 += __shfl_xor(a2, 16); a3 += __shfl_xor(a3, 16);
        a0 += __shfl_xor(a0, 32); a1 += __shfl_xor(a1, 32);
        a2 += __shfl_xor(a2, 32); a3 += __shfl_xor(a3, 32);
        if (q == 0) {
            f16x4 o;
            o[0] = (_Float16)fmaxf(fmaf(a0, di, bb.x), 0.f);
            o[1] = (_Float16)fmaxf(fmaf(a1, di, bb.y), 0.f);
            o[2] = (_Float16)fmaxf(fmaf(a2, di, bb.z), 0.f);
            o[3] = (_Float16)fmaxf(fmaf(a3, di, bb.w), 0.f);
            *(f16x4*)&A[(w * 8 + i) * 72 + r * 4] = o;
        }
    }
    __syncthreads();

    // ---- GEMM phase: wave w -> tile (w>>1), col-tiles {(w&1)*2, +1} ----
    const int lr = l & 15;
    const int lg = l >> 4;
    const int th = w >> 1;            // tile-half within block (0/1)
    const int ch = (w & 1) * 2;       // first col-tile

    f16x8 bf[2][2];
#pragma unroll
    for (int kt = 0; kt < 2; ++kt)
#pragma unroll
        for (int ct = 0; ct < 2; ++ct)
            bf[kt][ct] = *(const f16x8*)&Wt[((ch + ct) * 16 + lr) * 72 + kt * 32 + lg * 8];

    f16x8 af[2];
#pragma unroll
    for (int kt = 0; kt < 2; ++kt)
        af[kt] = *(const f16x8*)&A[(th * 16 + lr) * 72 + kt * 32 + lg * 8];

    f32x4 acc[2] = {{0.f,0.f,0.f,0.f},{0.f,0.f,0.f,0.f}};
#pragma unroll
    for (int kt = 0; kt < 2; ++kt)
#pragma unroll
        for (int ct = 0; ct < 2; ++ct)
            acc[ct] = __builtin_amdgcn_mfma_f32_16x16x32_f16(af[kt], bf[kt][ct], acc[ct], 0, 0, 0);

    const int rowb = nb + th * 16 + lg * 4;
    float4 sc4 = {0.f, 0.f, 0.f, 0.f};
    if (!PROJ) sc4 = *(const float4*)&isd[rowb];
    const float scv[4] = {sc4.x, sc4.y, sc4.z, sc4.w};
#pragma unroll
    for (int ct = 0; ct < 2; ++ct) {
        const int c = (ch + ct) * 16 + lr;
        float badd = 0.f;
        if (PROJ) badd = bout[c];
#pragma unroll
        for (int rr = 0; rr < 4; ++rr) {
            if (PROJ) outf[(size_t)(rowb + rr) * F + c] = acc[ct][rr] + badd;
            else      outh[(size_t)(rowb + rr) * F + c] = f2h(acc[ct][rr] * scv[rr]);
        }
    }
}

// ======================= launch =======================

extern "C" void kernel_launch(void* const* d_in, const int* in_sizes, int n_in,
                              void* d_out, int out_size, void* d_ws, size_t ws_size,
                              hipStream_t stream)
{
    const float* x   = (const float*)d_in[0];
    const int*   ei  = (const int*)d_in[1];
    const float* W1  = (const float*)d_in[2];
    const float* b1  = (const float*)d_in[3];
    const float* W2  = (const float*)d_in[4];
    const float* b2  = (const float*)d_in[5];
    const float* Wp  = (const float*)d_in[6];
    const float* bp  = (const float*)d_in[7];
    float*       z   = (float*)d_out;

    const int nN = in_sizes[0] / F;   // 100000
    const int nE = in_sizes[1] / 2;   // 1250000
    const int* srcp = ei;
    const int* dstp = ei + nE;

    // workspace layout (staging dead after sortP -> reused as mhB)
    char* ws = (char*)d_ws;
    size_t o = 0;
    auto alloc = [&](size_t bytes) { char* p = ws + o; o += (bytes + 255) & ~(size_t)255; return p; };
    float* isd    = (float*)alloc((size_t)nN * 4);
    int*   rowptr = (int*)  alloc(((size_t)nN + 1) * 4);
    int*   bbase  = (int*)  alloc((size_t)NPART * 16 * 4);
    int*   ebs    = (int*)  alloc((size_t)nE * 4);
    char*  U      = alloc((size_t)NPART * CAP * 8);          // staging 16.8MB >= mhB 12.8MB
    int2*  staging = (int2*)U;
    unsigned short* mhB = (unsigned short*)U;
    unsigned short* mhA = (unsigned short*)alloc((size_t)nN * F * 2);

    constexpr int EPT = 16;
    const int gbB    = (nE + 256 * EPT - 1) / (256 * EPT);   // 306 bin blocks
    const int nTiles = nN / 16;                              // 6250
    const int gbG    = (nTiles + 3) / 4;                     // 1563 gemm blocks
    const int gbF    = (nN + 31) / 32;                       // 3125 fused blocks

    // ---- CSR build (bin) overlapped with GEMM1 ----
    k_binit<<<1, NPART, 0, stream>>>(bbase);
    k_binGemm1<EPT><<<gbB + gbG, 256, 0, stream>>>(srcp, dstp, bbase, staging,
                                                   x, W1, mhA, nE, nN, gbB, nTiles);
    k_sortP<<<NPART, 256, 0, stream>>>(staging, bbase, ebs, rowptr, isd, mhA, nN, nE);

    // ---- layer 1+2 fused: agg(mhA') -> relu(+b1) -> @W2 -> mhB' (scaled) ----
    k_aggGemm<false><<<gbF, 256, 0, stream>>>(mhA, isd, rowptr, ebs, W2, b1, nullptr,
                                              mhB, nullptr, nN);
    // ---- layer 2+proj fused: agg(mhB') -> relu(+b2) -> @Wp + bp -> z ----
    k_aggGemm<true><<<gbF, 256, 0, stream>>>(mhB, isd, rowptr, ebs, Wp, b2, bp,
                                             nullptr, z, nN);
}

// Round 13
// 146.305 us; speedup vs baseline: 1.0780x; 1.0780x over previous
//
#include <hip/hip_runtime.h>

#define F 64
#define NPART 256
#define CAP 8192   // per-partition staging capacity; mean 4883 -> huge slack

typedef unsigned short u16x8 __attribute__((ext_vector_type(8)));
typedef _Float16       f16x8 __attribute__((ext_vector_type(8)));
typedef float          f32x4 __attribute__((ext_vector_type(4)));

// ---- fp16 helpers ----
__device__ __forceinline__ float h2f(unsigned short u) {
    _Float16 h; __builtin_memcpy(&h, &u, 2); return (float)h;
}
__device__ __forceinline__ unsigned short f2h(float f) {
    _Float16 h = (_Float16)f; unsigned short u; __builtin_memcpy(&u, &h, 2); return u;
}

// ======================= CSR build =======================

__global__ void k_binit(int* bbase) {
    bbase[threadIdx.x * 16] = threadIdx.x * CAP;
}

// Fused: blocks [0,nBin) bin edges; blocks [nBin,..) do GEMM1 (x @ W1 -> mhA,
// fp16, UNSCALED — k_sortP's tail scales by isd once isd exists).
template<int EPT>
__global__ __launch_bounds__(256)
void k_binGemm1(const int* __restrict__ src, const int* __restrict__ dst,
                int* bbase, int2* staging,
                const float* __restrict__ x, const float* __restrict__ W1,
                unsigned short* __restrict__ mhA,
                int nE, int nN, int nBin, int nTiles)
{
    __shared__ int lcnt[NPART];
    __shared__ int lbase[NPART];
    __shared__ _Float16 Wt[64 * 72];
    const int t = threadIdx.x;

    if (blockIdx.x < nBin) {
        // ---------------- bin path ----------------
        const int i0 = blockIdx.x * 256 * EPT;
        lcnt[t] = 0;
        __syncthreads();
        int es[EPT], ed[EPT], bk[EPT];
#pragma unroll
        for (int k = 0; k < EPT; ++k) {
            const int i = i0 + k * 256 + t;
            if (i < nE) {
                es[k] = src[i];
                ed[k] = dst[i];
                bk[k] = (int)(((long long)ed[k] * NPART) / nN);
                atomicAdd(&lcnt[bk[k]], 1);
            } else bk[k] = -1;
        }
        __syncthreads();
        lbase[t] = atomicAdd(&bbase[t * 16], lcnt[t]);
        lcnt[t] = 0;
        __syncthreads();
#pragma unroll
        for (int k = 0; k < EPT; ++k) {
            if (bk[k] >= 0) {
                const int r   = atomicAdd(&lcnt[bk[k]], 1);
                const int pos = lbase[bk[k]] + r;
                if (pos < (bk[k] + 1) * CAP)
                    staging[pos] = make_int2(es[k], ed[k]);
            }
        }
    } else {
        // ---------------- GEMM1 path (f32 in, no act, fp16 out) ----------------
#pragma unroll
        for (int i = 0; i < 16; ++i) {
            const int idx = i * 256 + t;
            Wt[(idx & 63) * 72 + (idx >> 6)] = (_Float16)W1[idx];
        }
        __syncthreads();
        const int w    = t >> 6;
        const int l    = t & 63;
        const int lr   = l & 15;
        const int lg   = l >> 4;
        const int tile = (blockIdx.x - nBin) * 4 + w;
        if (tile >= nTiles) return;

        f16x8 bf[2][4];
#pragma unroll
        for (int kt = 0; kt < 2; ++kt)
#pragma unroll
            for (int ct = 0; ct < 4; ++ct)
                bf[kt][ct] = *(const f16x8*)&Wt[(ct * 16 + lr) * 72 + kt * 32 + lg * 8];

        const float* rp = x + (size_t)(tile * 16 + lr) * F;
        f16x8 af[2];
#pragma unroll
        for (int kt = 0; kt < 2; ++kt) {
            const float4 v0 = *(const float4*)(rp + kt * 32 + lg * 8);
            const float4 v1 = *(const float4*)(rp + kt * 32 + lg * 8 + 4);
            f16x8 a;
            a[0] = (_Float16)v0.x; a[1] = (_Float16)v0.y;
            a[2] = (_Float16)v0.z; a[3] = (_Float16)v0.w;
            a[4] = (_Float16)v1.x; a[5] = (_Float16)v1.y;
            a[6] = (_Float16)v1.z; a[7] = (_Float16)v1.w;
            af[kt] = a;
        }

        f32x4 acc[4] = {{0.f,0.f,0.f,0.f},{0.f,0.f,0.f,0.f},{0.f,0.f,0.f,0.f},{0.f,0.f,0.f,0.f}};
#pragma unroll
        for (int kt = 0; kt < 2; ++kt)
#pragma unroll
            for (int ct = 0; ct < 4; ++ct)
                acc[ct] = __builtin_amdgcn_mfma_f32_16x16x32_f16(af[kt], bf[kt][ct], acc[ct], 0, 0, 0);

        const int rowb = tile * 16 + lg * 4;
#pragma unroll
        for (int ct = 0; ct < 4; ++ct) {
            const int c = ct * 16 + lr;
#pragma unroll
            for (int r = 0; r < 4; ++r)
                mhA[(size_t)(rowb + r) * F + c] = f2h(acc[ct][r]);
        }
    }
}

// One block (256 threads) per partition p: LDS counting sort of staging slice,
// then scale tail: mhA[row] *= isd[row] (pre-scaling for the gather).
__global__ __launch_bounds__(256)
void k_sortP(const int2* __restrict__ staging, const int* __restrict__ bbase,
             int* __restrict__ ebs, int* __restrict__ rowptr,
             float* __restrict__ isd, unsigned short* __restrict__ mhA,
             int nN, int nE) {
    __shared__ int pc[NPART];
    __shared__ int pcv[NPART];
    __shared__ int cnt[512];
    __shared__ int cur[512];
    const int p = blockIdx.x;
    const int t = threadIdx.x;

    int cval = bbase[t * 16] - t * CAP;
    if (cval > CAP) cval = CAP;
    if (cval < 0)   cval = 0;
    pc[t]  = cval;
    pcv[t] = cval;
    __syncthreads();
#pragma unroll
    for (int off = 1; off < NPART; off <<= 1) {
        const int a = (t >= off) ? pc[t - off] : 0;
        __syncthreads();
        pc[t] += a;
        __syncthreads();
    }
    const int cg    = pcv[p];
    const int ebase = pc[p] - cg;
    // EXACT inverse of bucket(): lo = ceil(p*nN/NPART)
    const int lo    = (int)(((long long)nN * p + NPART - 1) / NPART);
    const int hi    = (int)(((long long)nN * (p + 1) + NPART - 1) / NPART);
    const int npn   = hi - lo;

    cnt[t] = 0; cnt[t + 256] = 0;
    __syncthreads();
    const int2* st = staging + (size_t)p * CAP;
    for (int j = t; j < cg; j += 256) atomicAdd(&cnt[st[j].y - lo], 1);
    __syncthreads();

    const int c0 = cnt[t], c1 = cnt[t + 256];
#pragma unroll
    for (int off = 1; off < 512; off <<= 1) {
        const int a0 = (t >= off) ? cnt[t - off] : 0;
        const int a1 = (t + 256 >= off) ? cnt[t + 256 - off] : 0;
        __syncthreads();
        cnt[t] += a0; cnt[t + 256] += a1;
        __syncthreads();
    }
    const int e0 = cnt[t] - c0, e1 = cnt[t + 256] - c1;
    cur[t] = e0; cur[t + 256] = e1;

    if (t < npn)        { rowptr[lo + t]        = ebase + e0; isd[lo + t]        = rsqrtf((float)c0 + 1.0f); }
    if (t + 256 < npn)  { rowptr[lo + t + 256]  = ebase + e1; isd[lo + t + 256]  = rsqrtf((float)c1 + 1.0f); }
    if (p == NPART - 1 && t == 0) rowptr[nN] = ebase + cg;
    __syncthreads();

    for (int j = t; j < cg; j += 256) {
        const int2 e = st[j];
        const int  r = atomicAdd(&cur[e.y - lo], 1);
        ebs[ebase + r] = e.x;
    }

    // ---- scale tail: mhA[row] *= isd[row] for rows [lo, hi) ----
    for (int r = t; r < npn; r += 256) {
        const int row = lo + r;
        const float sr = isd[row];
        u16x8* rp = (u16x8*)(mhA + (size_t)row * F);
#pragma unroll
        for (int q = 0; q < 8; ++q) {
            u16x8 v = rp[q];
            u16x8 o;
#pragma unroll
            for (int j = 0; j < 8; ++j) o[j] = f2h(h2f(v[j]) * sr);
            rp[q] = o;
        }
    }
}

// ---- one masked gather step: acc += mask(ix<en) * mh'[ebs[clamp(ix)]][l] ----
// ix/en wave-uniform (SGPR); row load is a full-wave 128B coalesced load.
__device__ __forceinline__ void gstep(const unsigned short* __restrict__ mh,
                                      const int* __restrict__ ebs,
                                      int ix, int en, int l, float& acc) {
    int cl = (ix < en) ? ix : en - 1;
    cl = (cl < 0) ? 0 : cl;
    const float mk = (ix < en) ? 1.f : 0.f;
    acc = fmaf(mk, h2f(mh[(size_t)ebs[cl] * F + l]), acc);
}

// ======================= fused agg + GEMM =======================
// Block = 32 nodes, 4 waves; agg: wave w owns nodes nb+w*8 .. +7, processed as
// 2 groups of 4 SIMULTANEOUS streams -> 16 independent row loads in flight
// (vs one-node-at-a-time serial chains). Indices stay wave-uniform (scalar
// pipe); tails handled by clamp+mask (duplicate clamped rows hit cache).
// mh' pre-scaled by isd: acc = mh'[n] + sum_e mh'[s]; A = relu(acc*di + bin).
// GEMM: wave w -> 16-row tile (w>>1), col-tiles {(w&1)*2, +1}.
// Epilogue: PROJ ? z=f32(acc+bout) : mhOut = fp16(acc*isd[row]) (pre-scaled).
// nN must be a multiple of 32 (100000 = 3125*32).

template<bool PROJ>
__global__ __launch_bounds__(256)
void k_aggGemm(const unsigned short* __restrict__ mhIn,
               const float* __restrict__ isd,
               const int* __restrict__ rowptr, const int* __restrict__ ebs,
               const float* __restrict__ W, const float* __restrict__ bin,
               const float* __restrict__ bout,
               unsigned short* __restrict__ outh, float* __restrict__ outf,
               int nN)
{
    __shared__ _Float16 Wt[64 * 72];
    __shared__ _Float16 A[32 * 72];
    const int t = threadIdx.x;
#pragma unroll
    for (int i = 0; i < 16; ++i) {
        const int idx = i * 256 + t;
        Wt[(idx & 63) * 72 + (idx >> 6)] = (_Float16)W[idx];
    }

    const int w  = t >> 6;
    const int l  = t & 63;
    const int nb = blockIdx.x * 32;
    const float bl = bin[l];

#pragma unroll
    for (int g = 0; g < 2; ++g) {
        const int n0 = nb + w * 8 + g * 4;
        // consecutive CSR nodes share boundaries: 5 scalar loads
        const int b0 = __builtin_amdgcn_readfirstlane(rowptr[n0 + 0]);
        const int e0 = __builtin_amdgcn_readfirstlane(rowptr[n0 + 1]);
        const int e1 = __builtin_amdgcn_readfirstlane(rowptr[n0 + 2]);
        const int e2 = __builtin_amdgcn_readfirstlane(rowptr[n0 + 3]);
        const int e3 = __builtin_amdgcn_readfirstlane(rowptr[n0 + 4]);
        const int b1 = e0, b2 = e1, b3 = e2;

        const float di0 = isd[n0 + 0], di1 = isd[n0 + 1];
        const float di2 = isd[n0 + 2], di3 = isd[n0 + 3];
        // self terms (mh' = m*isd)
        float ac0 = h2f(mhIn[(size_t)(n0 + 0) * F + l]);
        float ac1 = h2f(mhIn[(size_t)(n0 + 1) * F + l]);
        float ac2 = h2f(mhIn[(size_t)(n0 + 2) * F + l]);
        float ac3 = h2f(mhIn[(size_t)(n0 + 3) * F + l]);

        const int d0 = e0 - b0, d1 = e1 - b1, d2 = e2 - b2, d3 = e3 - b3;
        int mx = d0 > d1 ? d0 : d1;
        if (d2 > mx) mx = d2;
        if (d3 > mx) mx = d3;

        for (int k = 0; k < mx; k += 4) {
#pragma unroll
            for (int j = 0; j < 4; ++j) gstep(mhIn, ebs, b0 + k + j, e0, l, ac0);
#pragma unroll
            for (int j = 0; j < 4; ++j) gstep(mhIn, ebs, b1 + k + j, e1, l, ac1);
#pragma unroll
            for (int j = 0; j < 4; ++j) gstep(mhIn, ebs, b2 + k + j, e2, l, ac2);
#pragma unroll
            for (int j = 0; j < 4; ++j) gstep(mhIn, ebs, b3 + k + j, e3, l, ac3);
        }

        _Float16* Ar = &A[(w * 8 + g * 4) * 72 + l];
        Ar[0 * 72] = (_Float16)fmaxf(fmaf(ac0, di0, bl), 0.f);
        Ar[1 * 72] = (_Float16)fmaxf(fmaf(ac1, di1, bl), 0.f);
        Ar[2 * 72] = (_Float16)fmaxf(fmaf(ac2, di2, bl), 0.f);
        Ar[3 * 72] = (_Float16)fmaxf(fmaf(ac3, di3, bl), 0.f);
    }
    __syncthreads();

    // ---- GEMM phase: wave w -> tile (w>>1), col-tiles {(w&1)*2, +1} ----
    const int lr = l & 15;
    const int lg = l >> 4;
    const int th = w >> 1;            // tile-half within block (0/1)
    const int ch = (w & 1) * 2;       // first col-tile

    f16x8 bf[2][2];
#pragma unroll
    for (int kt = 0; kt < 2; ++kt)
#pragma unroll
        for (int ct = 0; ct < 2; ++ct)
            bf[kt][ct] = *(const f16x8*)&Wt[((ch + ct) * 16 + lr) * 72 + kt * 32 + lg * 8];

    f16x8 af[2];
#pragma unroll
    for (int kt = 0; kt < 2; ++kt)
        af[kt] = *(const f16x8*)&A[(th * 16 + lr) * 72 + kt * 32 + lg * 8];

    f32x4 acc[2] = {{0.f,0.f,0.f,0.f},{0.f,0.f,0.f,0.f}};
#pragma unroll
    for (int kt = 0; kt < 2; ++kt)
#pragma unroll
        for (int ct = 0; ct < 2; ++ct)
            acc[ct] = __builtin_amdgcn_mfma_f32_16x16x32_f16(af[kt], bf[kt][ct], acc[ct], 0, 0, 0);

    const int rowb = nb + th * 16 + lg * 4;
    float4 sc4 = {0.f, 0.f, 0.f, 0.f};
    if (!PROJ) sc4 = *(const float4*)&isd[rowb];
    const float scv[4] = {sc4.x, sc4.y, sc4.z, sc4.w};
#pragma unroll
    for (int ct = 0; ct < 2; ++ct) {
        const int c = (ch + ct) * 16 + lr;
        float badd = 0.f;
        if (PROJ) badd = bout[c];
#pragma unroll
        for (int rr = 0; rr < 4; ++rr) {
            if (PROJ) outf[(size_t)(rowb + rr) * F + c] = acc[ct][rr] + badd;
            else      outh[(size_t)(rowb + rr) * F + c] = f2h(acc[ct][rr] * scv[rr]);
        }
    }
}

// ======================= launch =======================

extern "C" void kernel_launch(void* const* d_in, const int* in_sizes, int n_in,
                              void* d_out, int out_size, void* d_ws, size_t ws_size,
                              hipStream_t stream)
{
    const float* x   = (const float*)d_in[0];
    const int*   ei  = (const int*)d_in[1];
    const float* W1  = (const float*)d_in[2];
    const float* b1  = (const float*)d_in[3];
    const float* W2  = (const float*)d_in[4];
    const float* b2  = (const float*)d_in[5];
    const float* Wp  = (const float*)d_in[6];
    const float* bp  = (const float*)d_in[7];
    float*       z   = (float*)d_out;

    const int nN = in_sizes[0] / F;   // 100000
    const int nE = in_sizes[1] / 2;   // 1250000
    const int* srcp = ei;
    const int* dstp = ei + nE;

    // workspace layout (staging dead after sortP -> reused as mhB)
    char* ws = (char*)d_ws;
    size_t o = 0;
    auto alloc = [&](size_t bytes) { char* p = ws + o; o += (bytes + 255) & ~(size_t)255; return p; };
    float* isd    = (float*)alloc((size_t)nN * 4);
    int*   rowptr = (int*)  alloc(((size_t)nN + 1) * 4);
    int*   bbase  = (int*)  alloc((size_t)NPART * 16 * 4);
    int*   ebs    = (int*)  alloc((size_t)nE * 4);
    char*  U      = alloc((size_t)NPART * CAP * 8);          // staging 16.8MB >= mhB 12.8MB
    int2*  staging = (int2*)U;
    unsigned short* mhB = (unsigned short*)U;
    unsigned short* mhA = (unsigned short*)alloc((size_t)nN * F * 2);

    constexpr int EPT = 16;
    const int gbB    = (nE + 256 * EPT - 1) / (256 * EPT);   // 306 bin blocks
    const int nTiles = nN / 16;                              // 6250
    const int gbG    = (nTiles + 3) / 4;                     // 1563 gemm blocks
    const int gbF    = (nN + 31) / 32;                       // 3125 fused blocks

    // ---- CSR build (bin) overlapped with GEMM1 ----
    k_binit<<<1, NPART, 0, stream>>>(bbase);
    k_binGemm1<EPT><<<gbB + gbG, 256, 0, stream>>>(srcp, dstp, bbase, staging,
                                                   x, W1, mhA, nE, nN, gbB, nTiles);
    k_sortP<<<NPART, 256, 0, stream>>>(staging, bbase, ebs, rowptr, isd, mhA, nN, nE);

    // ---- layer 1+2 fused: agg(mhA') -> relu(+b1) -> @W2 -> mhB' (scaled) ----
    k_aggGemm<false><<<gbF, 256, 0, stream>>>(mhA, isd, rowptr, ebs, W2, b1, nullptr,
                                              mhB, nullptr, nN);
    // ---- layer 2+proj fused: agg(mhB') -> relu(+b2) -> @Wp + bp -> z ----
    k_aggGemm<true><<<gbF, 256, 0, stream>>>(mhB, isd, rowptr, ebs, Wp, b2, bp,
                                             nullptr, z, nN);
}

// Round 14
// 129.877 us; speedup vs baseline: 1.2144x; 1.1265x over previous
//
#include <hip/hip_runtime.h>

#define F 64
#define NPART 256
#define CAP 8192   // per-partition staging capacity; mean 4883 -> huge slack

typedef unsigned short u16x8 __attribute__((ext_vector_type(8)));
typedef _Float16       f16x8 __attribute__((ext_vector_type(8)));
typedef _Float16       f16x2 __attribute__((ext_vector_type(2)));
typedef float          f32x4 __attribute__((ext_vector_type(4)));

// ---- fp16 helpers ----
__device__ __forceinline__ float h2f(unsigned short u) {
    _Float16 h; __builtin_memcpy(&h, &u, 2); return (float)h;
}
__device__ __forceinline__ unsigned short f2h(float f) {
    _Float16 h = (_Float16)f; unsigned short u; __builtin_memcpy(&u, &h, 2); return u;
}

// ======================= CSR build =======================

// Fused: blocks [0,nBin) bin edges; blocks [nBin,..) do GEMM1 (x @ W1 -> mhA,
// fp16, UNSCALED — k_sortP's tail scales by isd once isd exists).
// bbase counters start at 0 (memsetAsync); slot base = t*CAP + cursor.
template<int EPT>
__global__ __launch_bounds__(256)
void k_binGemm1(const int* __restrict__ src, const int* __restrict__ dst,
                int* bbase, int2* staging,
                const float* __restrict__ x, const float* __restrict__ W1,
                unsigned short* __restrict__ mhA,
                int nE, int nN, int nBin, int nTiles)
{
    __shared__ int lcnt[NPART];
    __shared__ int lbase[NPART];
    __shared__ _Float16 Wt[64 * 72];
    const int t = threadIdx.x;

    if (blockIdx.x < nBin) {
        // ---------------- bin path ----------------
        const int i0 = blockIdx.x * 256 * EPT;
        lcnt[t] = 0;
        __syncthreads();
        int es[EPT], ed[EPT], bk[EPT];
#pragma unroll
        for (int k = 0; k < EPT; ++k) {
            const int i = i0 + k * 256 + t;
            if (i < nE) {
                es[k] = src[i];
                ed[k] = dst[i];
                bk[k] = (int)(((long long)ed[k] * NPART) / nN);
                atomicAdd(&lcnt[bk[k]], 1);
            } else bk[k] = -1;
        }
        __syncthreads();
        lbase[t] = t * CAP + atomicAdd(&bbase[t * 16], lcnt[t]);
        lcnt[t] = 0;
        __syncthreads();
#pragma unroll
        for (int k = 0; k < EPT; ++k) {
            if (bk[k] >= 0) {
                const int r   = atomicAdd(&lcnt[bk[k]], 1);
                const int pos = lbase[bk[k]] + r;
                if (pos < (bk[k] + 1) * CAP)            // overflow guard (never expected)
                    staging[pos] = make_int2(es[k], ed[k]);
            }
        }
    } else {
        // ---------------- GEMM1 path (f32 in, no act, fp16 out) ----------------
#pragma unroll
        for (int i = 0; i < 16; ++i) {
            const int idx = i * 256 + t;
            Wt[(idx & 63) * 72 + (idx >> 6)] = (_Float16)W1[idx];
        }
        __syncthreads();
        const int w    = t >> 6;
        const int l    = t & 63;
        const int lr   = l & 15;
        const int lg   = l >> 4;
        const int tile = (blockIdx.x - nBin) * 4 + w;
        if (tile >= nTiles) return;

        f16x8 bf[2][4];
#pragma unroll
        for (int kt = 0; kt < 2; ++kt)
#pragma unroll
            for (int ct = 0; ct < 4; ++ct)
                bf[kt][ct] = *(const f16x8*)&Wt[(ct * 16 + lr) * 72 + kt * 32 + lg * 8];

        const float* rp = x + (size_t)(tile * 16 + lr) * F;
        f16x8 af[2];
#pragma unroll
        for (int kt = 0; kt < 2; ++kt) {
            const float4 v0 = *(const float4*)(rp + kt * 32 + lg * 8);
            const float4 v1 = *(const float4*)(rp + kt * 32 + lg * 8 + 4);
            f16x8 a;
            a[0] = (_Float16)v0.x; a[1] = (_Float16)v0.y;
            a[2] = (_Float16)v0.z; a[3] = (_Float16)v0.w;
            a[4] = (_Float16)v1.x; a[5] = (_Float16)v1.y;
            a[6] = (_Float16)v1.z; a[7] = (_Float16)v1.w;
            af[kt] = a;
        }

        f32x4 acc[4] = {{0.f,0.f,0.f,0.f},{0.f,0.f,0.f,0.f},{0.f,0.f,0.f,0.f},{0.f,0.f,0.f,0.f}};
#pragma unroll
        for (int kt = 0; kt < 2; ++kt)
#pragma unroll
            for (int ct = 0; ct < 4; ++ct)
                acc[ct] = __builtin_amdgcn_mfma_f32_16x16x32_f16(af[kt], bf[kt][ct], acc[ct], 0, 0, 0);

        const int rowb = tile * 16 + lg * 4;
#pragma unroll
        for (int ct = 0; ct < 4; ++ct) {
            const int c = ct * 16 + lr;
#pragma unroll
            for (int r = 0; r < 4; ++r)
                mhA[(size_t)(rowb + r) * F + c] = f2h(acc[ct][r]);
        }
    }
}

// One block (256 threads) per partition p: LDS counting sort of staging slice,
// then scale tail: mhA[row] *= isd[row] (pre-scaling for the gather).
__global__ __launch_bounds__(256)
void k_sortP(const int2* __restrict__ staging, const int* __restrict__ bbase,
             int* __restrict__ ebs, int* __restrict__ rowptr,
             float* __restrict__ isd, unsigned short* __restrict__ mhA,
             int nN, int nE) {
    __shared__ int pc[NPART];
    __shared__ int pcv[NPART];
    __shared__ int cnt[512];
    __shared__ int cur[512];
    const int p = blockIdx.x;
    const int t = threadIdx.x;

    int cval = bbase[t * 16];            // count directly (cursor started at 0)
    if (cval > CAP) cval = CAP;
    if (cval < 0)   cval = 0;
    pc[t]  = cval;
    pcv[t] = cval;
    __syncthreads();
#pragma unroll
    for (int off = 1; off < NPART; off <<= 1) {
        const int a = (t >= off) ? pc[t - off] : 0;
        __syncthreads();
        pc[t] += a;
        __syncthreads();
    }
    const int cg    = pcv[p];
    const int ebase = pc[p] - cg;
    // EXACT inverse of bucket(): lo = ceil(p*nN/NPART)
    const int lo    = (int)(((long long)nN * p + NPART - 1) / NPART);
    const int hi    = (int)(((long long)nN * (p + 1) + NPART - 1) / NPART);
    const int npn   = hi - lo;

    cnt[t] = 0; cnt[t + 256] = 0;
    __syncthreads();
    const int2* st = staging + (size_t)p * CAP;
    for (int j = t; j < cg; j += 256) atomicAdd(&cnt[st[j].y - lo], 1);
    __syncthreads();

    const int c0 = cnt[t], c1 = cnt[t + 256];
#pragma unroll
    for (int off = 1; off < 512; off <<= 1) {
        const int a0 = (t >= off) ? cnt[t - off] : 0;
        const int a1 = (t + 256 >= off) ? cnt[t + 256 - off] : 0;
        __syncthreads();
        cnt[t] += a0; cnt[t + 256] += a1;
        __syncthreads();
    }
    const int e0 = cnt[t] - c0, e1 = cnt[t + 256] - c1;
    cur[t] = e0; cur[t + 256] = e1;

    if (t < npn)        { rowptr[lo + t]        = ebase + e0; isd[lo + t]        = rsqrtf((float)c0 + 1.0f); }
    if (t + 256 < npn)  { rowptr[lo + t + 256]  = ebase + e1; isd[lo + t + 256]  = rsqrtf((float)c1 + 1.0f); }
    if (p == NPART - 1 && t == 0) rowptr[nN] = ebase + cg;
    __syncthreads();

    for (int j = t; j < cg; j += 256) {
        const int2 e = st[j];
        const int  r = atomicAdd(&cur[e.y - lo], 1);
        ebs[ebase + r] = e.x;
    }

    // ---- scale tail: mhA[row] *= isd[row] for rows [lo, hi) ----
    for (int r = t; r < npn; r += 256) {
        const int row = lo + r;
        const float sr = isd[row];
        u16x8* rp = (u16x8*)(mhA + (size_t)row * F);
#pragma unroll
        for (int q = 0; q < 8; ++q) {
            u16x8 v = rp[q];
            u16x8 o;
#pragma unroll
            for (int j = 0; j < 8; ++j) o[j] = f2h(h2f(v[j]) * sr);
            rp[q] = o;
        }
    }
}

// ---- packed gather step: one dword load covers 2 rows (lo half / hi half) ----
// sLo/sHi wave-uniform (SGPR); row select is a v_cndmask. Lane l holds
// features [2*(l&31), +1] of row (l>=32 ? sHi : sLo).
__device__ __forceinline__ void g2(const unsigned short* __restrict__ mh,
                                   int sLo, int sHi, int hl, int j2,
                                   float& a0, float& a1) {
    const int row = hl ? sHi : sLo;
    const f16x2 v = *(const f16x2*)(mh + (size_t)row * F + j2);
    a0 += (float)v[0];
    a1 += (float)v[1];
}

// ======================= fused agg + GEMM =======================
// Block = 32 nodes, 4 waves; agg: wave w owns nodes nb+w*8 .. +7 (unrolled ->
// cross-node ILP). Packed 2-rows-per-dword gather; indices stay scalar.
// Per node: main 8 edges / 4 instrs, mid 2 edges / 1 instr, last masked.
// Epilogue: shfl_xor(32) half-sum, lanes<32 write relu(acc*di + bin) as f16x2.
// mh' pre-scaled by isd so the edge loop has NO weight loads.
// GEMM: wave w -> 16-row tile (w>>1), col-tiles {(w&1)*2, +1}.
// Epilogue: PROJ ? z=f32(acc+bout) : mhOut = fp16(acc*isd[row]) (pre-scaled).
// nN must be a multiple of 32 (100000 = 3125*32).

template<bool PROJ>
__global__ __launch_bounds__(256)
void k_aggGemm(const unsigned short* __restrict__ mhIn,
               const float* __restrict__ isd,
               const int* __restrict__ rowptr, const int* __restrict__ ebs,
               const float* __restrict__ W, const float* __restrict__ bin,
               const float* __restrict__ bout,
               unsigned short* __restrict__ outh, float* __restrict__ outf,
               int nN)
{
    __shared__ _Float16 Wt[64 * 72];
    __shared__ _Float16 A[32 * 72];
    const int t = threadIdx.x;
#pragma unroll
    for (int i = 0; i < 16; ++i) {
        const int idx = i * 256 + t;
        Wt[(idx & 63) * 72 + (idx >> 6)] = (_Float16)W[idx];
    }

    const int w   = t >> 6;
    const int l   = t & 63;
    const int hl  = l >> 5;            // row half (0/1)
    const int j2  = (l & 31) * 2;      // feature pair base
    const int nb  = blockIdx.x * 32;
    const float hsel = (hl == 0) ? 1.f : 0.f;
    const float2 bb  = *(const float2*)(bin + j2);   // bias for features j2, j2+1

#pragma unroll
    for (int i = 0; i < 8; ++i) {
        const int n = nb + w * 8 + i;
        const int beg = __builtin_amdgcn_readfirstlane(rowptr[n]);
        const int end = __builtin_amdgcn_readfirstlane(rowptr[n + 1]);
        const float di = isd[n];
        // self term (mh' = m*isd), hi half masked so it counts once
        const f16x2 sv = *(const f16x2*)(mhIn + (size_t)n * F + j2);
        float a0 = hsel * (float)sv[0];
        float a1 = hsel * (float)sv[1];
        int e = beg;
        for (; e + 8 <= end; e += 8) {       // 8 edges, 4 instructions
            const int s0 = ebs[e + 0], s1 = ebs[e + 1], s2 = ebs[e + 2], s3 = ebs[e + 3];
            const int s4 = ebs[e + 4], s5 = ebs[e + 5], s6 = ebs[e + 6], s7 = ebs[e + 7];
            g2(mhIn, s0, s1, hl, j2, a0, a1);
            g2(mhIn, s2, s3, hl, j2, a0, a1);
            g2(mhIn, s4, s5, hl, j2, a0, a1);
            g2(mhIn, s6, s7, hl, j2, a0, a1);
        }
        for (; e + 2 <= end; e += 2) {       // 2 edges, 1 instruction
            const int s0 = ebs[e + 0], s1 = ebs[e + 1];
            g2(mhIn, s0, s1, hl, j2, a0, a1);
        }
        if (e < end) {                        // last edge: hi half masked
            const int s0 = ebs[e];
            const f16x2 v = *(const f16x2*)(mhIn + (size_t)s0 * F + j2);
            a0 = fmaf(hsel, (float)v[0], a0);
            a1 = fmaf(hsel, (float)v[1], a1);
        }
        // combine the two row-halves
        a0 += __shfl_xor(a0, 32);
        a1 += __shfl_xor(a1, 32);
        if (hl == 0) {
            f16x2 o;
            o[0] = (_Float16)fmaxf(fmaf(a0, di, bb.x), 0.f);
            o[1] = (_Float16)fmaxf(fmaf(a1, di, bb.y), 0.f);
            *(f16x2*)&A[(w * 8 + i) * 72 + j2] = o;
        }
    }
    __syncthreads();

    // ---- GEMM phase: wave w -> tile (w>>1), col-tiles {(w&1)*2, +1} ----
    const int lr = l & 15;
    const int lg = l >> 4;
    const int th = w >> 1;            // tile-half within block (0/1)
    const int ch = (w & 1) * 2;       // first col-tile

    f16x8 bf[2][2];
#pragma unroll
    for (int kt = 0; kt < 2; ++kt)
#pragma unroll
        for (int ct = 0; ct < 2; ++ct)
            bf[kt][ct] = *(const f16x8*)&Wt[((ch + ct) * 16 + lr) * 72 + kt * 32 + lg * 8];

    f16x8 af[2];
#pragma unroll
    for (int kt = 0; kt < 2; ++kt)
        af[kt] = *(const f16x8*)&A[(th * 16 + lr) * 72 + kt * 32 + lg * 8];

    f32x4 acc[2] = {{0.f,0.f,0.f,0.f},{0.f,0.f,0.f,0.f}};
#pragma unroll
    for (int kt = 0; kt < 2; ++kt)
#pragma unroll
        for (int ct = 0; ct < 2; ++ct)
            acc[ct] = __builtin_amdgcn_mfma_f32_16x16x32_f16(af[kt], bf[kt][ct], acc[ct], 0, 0, 0);

    const int rowb = nb + th * 16 + lg * 4;
    float4 sc4 = {0.f, 0.f, 0.f, 0.f};
    if (!PROJ) sc4 = *(const float4*)&isd[rowb];
    const float scv[4] = {sc4.x, sc4.y, sc4.z, sc4.w};
#pragma unroll
    for (int ct = 0; ct < 2; ++ct) {
        const int c = (ch + ct) * 16 + lr;
        float badd = 0.f;
        if (PROJ) badd = bout[c];
#pragma unroll
        for (int rr = 0; rr < 4; ++rr) {
            if (PROJ) outf[(size_t)(rowb + rr) * F + c] = acc[ct][rr] + badd;
            else      outh[(size_t)(rowb + rr) * F + c] = f2h(acc[ct][rr] * scv[rr]);
        }
    }
}

// ======================= launch =======================

extern "C" void kernel_launch(void* const* d_in, const int* in_sizes, int n_in,
                              void* d_out, int out_size, void* d_ws, size_t ws_size,
                              hipStream_t stream)
{
    const float* x   = (const float*)d_in[0];
    const int*   ei  = (const int*)d_in[1];
    const float* W1  = (const float*)d_in[2];
    const float* b1  = (const float*)d_in[3];
    const float* W2  = (const float*)d_in[4];
    const float* b2  = (const float*)d_in[5];
    const float* Wp  = (const float*)d_in[6];
    const float* bp  = (const float*)d_in[7];
    float*       z   = (float*)d_out;

    const int nN = in_sizes[0] / F;   // 100000
    const int nE = in_sizes[1] / 2;   // 1250000
    const int* srcp = ei;
    const int* dstp = ei + nE;

    // workspace layout (staging dead after sortP -> reused as mhB)
    char* ws = (char*)d_ws;
    size_t o = 0;
    auto alloc = [&](size_t bytes) { char* p = ws + o; o += (bytes + 255) & ~(size_t)255; return p; };
    float* isd    = (float*)alloc((size_t)nN * 4);
    int*   rowptr = (int*)  alloc(((size_t)nN + 1) * 4);
    int*   bbase  = (int*)  alloc((size_t)NPART * 16 * 4);
    int*   ebs    = (int*)  alloc((size_t)nE * 4);
    char*  U      = alloc((size_t)NPART * CAP * 8);          // staging 16.8MB >= mhB 12.8MB
    int2*  staging = (int2*)U;
    unsigned short* mhB = (unsigned short*)U;
    unsigned short* mhA = (unsigned short*)alloc((size_t)nN * F * 2);

    constexpr int EPT = 16;
    const int gbB    = (nE + 256 * EPT - 1) / (256 * EPT);   // 306 bin blocks
    const int nTiles = nN / 16;                              // 6250
    const int gbG    = (nTiles + 3) / 4;                     // 1563 gemm blocks
    const int gbF    = (nN + 31) / 32;                       // 3125 fused blocks

    // ---- CSR build (bin) overlapped with GEMM1 ----
    hipMemsetAsync(bbase, 0, (size_t)NPART * 16 * 4, stream);
    k_binGemm1<EPT><<<gbB + gbG, 256, 0, stream>>>(srcp, dstp, bbase, staging,
                                                   x, W1, mhA, nE, nN, gbB, nTiles);
    k_sortP<<<NPART, 256, 0, stream>>>(staging, bbase, ebs, rowptr, isd, mhA, nN, nE);

    // ---- layer 1+2 fused: agg(mhA') -> relu(+b1) -> @W2 -> mhB' (scaled) ----
    k_aggGemm<false><<<gbF, 256, 0, stream>>>(mhA, isd, rowptr, ebs, W2, b1, nullptr,
                                              mhB, nullptr, nN);
    // ---- layer 2+proj fused: agg(mhB') -> relu(+b2) -> @Wp + bp -> z ----
    k_aggGemm<true><<<gbF, 256, 0, stream>>>(mhB, isd, rowptr, ebs, Wp, b2, bp,
                                             nullptr, z, nN);
}